// Round 13
// baseline (209.729 us; speedup 1.0000x reference)
//
#include <hip/hip_runtime.h>
#include <math.h>

#define NN 40000
#define NP 40064          // 313 * 128, padded node count
#define CC 128
#define KK 64
#define BATCH 2
#define NLAYER 4
#define FSPLITS 128
#define MODES 144         // 64 cos + 64 sin + 1 mask-mode + 15 zero pad
#define KTOT 256          // inverse GEMM contraction: 64 bc + 64 bs + 128 h
#define NCH 626           // NP / 64
#define NVCH 625          // chunks with valid nodes (625*64 == NN exactly)

typedef __attribute__((ext_vector_type(8))) short bf16x8;
typedef __attribute__((ext_vector_type(4))) float f32x4;
typedef __attribute__((ext_vector_type(4))) unsigned short u16x4;
typedef __attribute__((ext_vector_type(8))) unsigned short u16x8;

__device__ __forceinline__ float gelu_exact(float x) {
    return 0.5f * x * (1.0f + erff(x * 0.70710678118654752f));
}
__device__ __forceinline__ unsigned short f2bf(float x) {   // RNE float->bf16
    unsigned int u = __float_as_uint(x);
    u += 0x7FFFu + ((u >> 16) & 1u);
    return (unsigned short)(u >> 16);
}
__device__ __forceinline__ float bf2f(unsigned short v) {
    return __uint_as_float(((unsigned int)v) << 16);
}
// barrier ordering LDS only: prefetch loads / global stores stay in flight across it
__device__ __forceinline__ void bar_lgkm() {
    asm volatile("s_waitcnt lgkmcnt(0)" ::: "memory");
    __builtin_amdgcn_s_barrier();
}

// ---------- fc1 transpose to [f][c] bf16 ----------
__global__ void fc1t_kernel(const float* __restrict__ fc1, unsigned short* __restrict__ fc1t) {
    int idx = blockIdx.x * 256 + threadIdx.x;    // 16384
    int f = idx >> 7, c = idx & 127;
    fc1t[f * 128 + c] = f2bf(fc1[c * 128 + f]);
}

// ---------- lift + basis + layer-0 forward partials (fully fused) ----------
__global__ __launch_bounds__(512) void lift_fused(const float* __restrict__ x,
        const float* __restrict__ w, const float* __restrict__ bvec,
        const float* __restrict__ nodes, const float* __restrict__ mask,
        const float* __restrict__ wts, const float* __restrict__ modes,
        unsigned short* __restrict__ Binv, float* __restrict__ maskp,
        float* __restrict__ warr, unsigned short* __restrict__ pxcs) {
    int s = blockIdx.x, b = blockIdx.y;
    int t = threadIdx.x, wv = t >> 6, l = t & 63, lo = l & 15, hi = l >> 4;
    __shared__ __align__(16) char lds[53504];
    char* Ts   = lds;              // [64 n][128 c]u16 (16 KB), h, swizzled
    char* Ts2  = lds + 16384;      // [128 c][64 n]u16 (16 KB), h*w, swizzled
    char* Wt   = lds + 32768;      // [144 mode][64 n]u16 rows 128B (18432 B)
    float* xl  = (float*)(lds + 51200);   // x chunk [64][3]  (768 B)
    float* ndl = (float*)(lds + 51968);   // nodes [64][2]    (512 B)
    float* wl  = (float*)(lds + 52480);   // w per n          (256 B)
    float* ml  = (float*)(lds + 52736);   // m per n          (256 B)
    float* sm  = (float*)(lds + 52992);   // modes [64][2]    (512 B)
    int c = t & 127, ng = t >> 7;
    float w0 = w[c], w1 = w[CC + c], w2 = w[2 * CC + c], bv = bvec[c];
    f32x4 accF[9];
    #pragma unroll
    for (int mt = 0; mt < 9; ++mt) accF[mt] = (f32x4){0.f, 0.f, 0.f, 0.f};
    if (t < 128) sm[t] = modes[t];
    if (t < 480) *(unsigned int*)(Wt + 129 * 128 + t * 4) = 0u;   // zero pad rows once

    auto fetch = [&](int chunk) -> float {
        if (chunk >= NVCH) return 0.f;   // pad chunk
        long base = (long)b * NN + chunk * 64;
        if (t < 192) return x[base * 3 + t];
        if (t < 320) return nodes[base * 2 + (t - 192)];
        if (t < 384) return wts[base + (t - 320)];
        if (t < 448) return mask[base + (t - 384)];
        return 0.f;
    };
    float pf = fetch(s);

    for (int chunk = s; chunk < NCH; chunk += FSPLITS) {
        int nbase = chunk * 64;
        bar_lgkm();   // (a) prev iter's Ts/Ts2/Wt reads complete
        {   // commit prefetched float
            if (t < 192)      xl[t] = pf;
            else if (t < 320) ndl[t - 192] = pf;
            else if (t < 384) wl[t - 320] = pf;
            else if (t < 448) ml[t - 384] = pf;
        }
        int nc = chunk + FSPLITS;
        if (nc < NCH) pf = fetch(nc);
        bar_lgkm();   // (b)
        {   // sincos role: thread = (n_, 8 modes); write Wt + Binv bc/bs
            int n_ = t & 63, g = t >> 6;
            float nx = ndl[n_ * 2], ny = ndl[n_ * 2 + 1];
            float m = ml[n_];
            u16x8 cosr, sinr;
            #pragma unroll
            for (int j = 0; j < 8; ++j) {
                int k = g * 8 + j;
                float tv = nx * sm[2 * k] + ny * sm[2 * k + 1];
                float sv, cv;
                __sincosf(tv, &sv, &cv);
                unsigned short cb = f2bf(cv * m), sb = f2bf(sv * m);
                cosr[j] = cb; sinr[j] = sb;
                *(unsigned short*)(Wt + ((k * 128 + n_ * 2) ^ ((k & 7) << 4))) = cb;
                *(unsigned short*)(Wt + (((64 + k) * 128 + n_ * 2) ^ (((64 + k) & 7) << 4))) = sb;
            }
            char* brow = (char*)Binv + ((long)b * NP + nbase + n_) * 512 + g * 16;
            *(u16x8*)brow = cosr;
            *(u16x8*)(brow + 128) = sinr;
            if (t < 64) {
                *(unsigned short*)(Wt + 128 * 128 + n_ * 2) = f2bf(m);
                maskp[(long)b * NP + nbase + n_] = m;
                warr[(long)b * NP + nbase + n_] = wl[n_];
            }
        }
        {   // h role: compute h, write Ts (h) and Ts2 (h*w)
            u16x8 hv0, hv1;
            #pragma unroll
            for (int j = 0; j < 16; ++j) {
                int n = ng * 16 + j;
                float h = bv + xl[n * 3] * w0 + xl[n * 3 + 1] * w1 + xl[n * 3 + 2] * w2;
                unsigned short hb = f2bf(h);
                unsigned short hwb = f2bf(h * wl[n]);
                if (j < 8) hv0[j] = hwb; else hv1[j - 8] = hwb;
                *(unsigned short*)(Ts + (((n << 8) + c * 2) ^ ((n & 7) << 4))) = hb;
            }
            int base2 = c * 128 + ng * 32;
            *(u16x8*)(Ts2 + (base2 ^ ((c & 7) << 4))) = hv0;
            *(u16x8*)(Ts2 + ((base2 + 16) ^ ((c & 7) << 4))) = hv1;
        }
        bar_lgkm();   // (c)
        char* Bdst = (char*)Binv + ((long)b * NP + nbase) * 512 + 256;
        #pragma unroll
        for (int pass = 0; pass < 2; ++pass) {
            int n = pass * 32 + (t >> 4), seg = t & 15;
            uint4 v = *(const uint4*)(Ts + (((n << 8) + (seg << 4)) ^ ((n & 7) << 4)));
            *(uint4*)(Bdst + (long)n * 512 + seg * 16) = v;
        }
        int ct = wv * 16;
        #pragma unroll
        for (int ks2 = 0; ks2 < 2; ++ks2) {
            int ar = ct + lo;
            bf16x8 a = *(const bf16x8*)(Ts2 + ((ar * 128 + ks2 * 64 + hi * 16) ^ ((ar & 7) << 4)));
            #pragma unroll
            for (int mt = 0; mt < 9; ++mt) {
                int mrow = mt * 16 + lo;
                bf16x8 bb = *(const bf16x8*)(Wt + ((mrow * 128 + ks2 * 64 + hi * 16) ^ ((mrow & 7) << 4)));
                accF[mt] = __builtin_amdgcn_mfma_f32_16x16x32_bf16(a, bb, accF[mt], 0, 0, 0);
            }
        }
    }
    unsigned short* pb = pxcs + ((long)s * BATCH + b) * CC * MODES;
    #pragma unroll
    for (int mt = 0; mt < 9; ++mt)
        #pragma unroll
        for (int r = 0; r < 4; ++r)
            pb[(long)(wv * 16 + hi * 4 + r) * MODES + mt * 16 + lo] = f2bf(accF[mt][r]);
}

// ---------- reduce split partials (bf16) -> xc, xs, x0 ----------
__global__ __launch_bounds__(256) void reduce_kernel(const unsigned short* __restrict__ pxcs,
        float* __restrict__ xc, float* __restrict__ xs, float* __restrict__ x0) {
    int gid = blockIdx.x * 256 + threadIdx.x;    // 8 * 36864 = 294912 total
    int idx = gid >> 3, sg = gid & 7;
    float a = 0.f;
    #pragma unroll
    for (int j = 0; j < 16; ++j)
        a += bf2f(pxcs[(long)(sg * 16 + j) * (BATCH * CC * MODES) + idx]);
    a += __shfl_xor(a, 1); a += __shfl_xor(a, 2); a += __shfl_xor(a, 4);
    if (sg == 0) {
        int m = idx % MODES, bc_ = idx / MODES;
        if (m < 64)        xc[bc_ * KK + m] = a;
        else if (m < 128)  xs[bc_ * KK + m - 64] = a;
        else if (m == 128) x0[bc_] = a;
    }
}

// ---------- mix: assemble A=[2fc|-2fs|ww] bf16, f0/wb fp32 (16 i-groups for TLP) ----------
__global__ __launch_bounds__(1024) void mix_kernel(const float* __restrict__ xc,
        const float* __restrict__ xs, const float* __restrict__ x0,
        const float* __restrict__ wc, const float* __restrict__ wsp,
        const float* __restrict__ w0, const float* __restrict__ ww,
        const float* __restrict__ wbias, unsigned short* __restrict__ A,
        float* __restrict__ f0a, float* __restrict__ wba, int layer) {
    int o = blockIdx.x, b = blockIdx.y;
    int k = threadIdx.x & 63, ig = threadIdx.x >> 6;   // ig 0..15
    const float* wcl = wc  + (long)layer * CC * CC * KK;
    const float* wsl = wsp + (long)layer * CC * CC * KK;
    float fc = 0.f, fs = 0.f;
    #pragma unroll
    for (int j = 0; j < 8; ++j) {
        int i = ig * 8 + j;
        float xci = xc[(b * CC + i) * KK + k];
        float xsi = xs[(b * CC + i) * KK + k];
        float wcv = wcl[((long)i * CC + o) * KK + k];
        float wsv = wsl[((long)i * CC + o) * KK + k];
        fc += xci * wcv + xsi * wsv;
        fs += xci * wsv - xsi * wcv;
    }
    __shared__ float rc[16][64], rs[16][64];
    rc[ig][k] = fc; rs[ig][k] = fs;
    __syncthreads();
    unsigned short* Ar = A + ((long)b * CC + o) * KTOT;
    if (ig == 0) {
        fc = 0.f; fs = 0.f;
        #pragma unroll
        for (int j = 0; j < 16; ++j) { fc += rc[j][k]; fs += rs[j][k]; }
        Ar[k]      = f2bf(2.f * fc);
        Ar[64 + k] = f2bf(-2.f * fs);
    } else if (ig == 1) {
        const float* wwl = ww + ((long)layer * CC + o) * CC;
        Ar[128 + k] = f2bf(wwl[k]);
        Ar[192 + k] = f2bf(wwl[64 + k]);
    } else if (ig == 2) {
        const float* w0l = w0 + (long)layer * CC * CC;
        float p = x0[b * CC + k] * w0l[(long)k * CC + o]
                + x0[b * CC + 64 + k] * w0l[(long)(64 + k) * CC + o];
        #pragma unroll
        for (int off = 32; off > 0; off >>= 1) p += __shfl_down(p, off, 64);
        if (k == 0) { f0a[b * CC + o] = p; wba[b * CC + o] = wbias[layer * CC + o]; }
    }
}

// ---------- fused inverse + next-layer forward partials (double-buffered, 2 barriers/chunk) ----------
// grid (FSPLITS, BATCH), 512 thr = 8 waves = 4 o-groups x 2 n-groups; wave tile 32o x 32n.
// Bt[2] ping-pong: commit of chunk i+1 overlaps MFMA of chunk i; Ts/Ts2/Wt separate (no overlay).
template <int DO_FWD, int DOGELU>
__global__ __launch_bounds__(512) void fused_inv(const unsigned short* __restrict__ Amat,
        unsigned short* Binv, const float* __restrict__ f0a, const float* __restrict__ wba,
        const float* __restrict__ maskp, const float* __restrict__ warr,
        unsigned short* __restrict__ pxcs) {
    int s = blockIdx.x, b = blockIdx.y;
    int t = threadIdx.x, wv = t >> 6, l = t & 63, lo = l & 15, hi = l >> 4;
    int wo = wv & 3, wn = wv >> 2;
    int obase = wo * 32, nwin = wn * 32;
    __shared__ __align__(16) char lds[117760];
    // Bt0: 0..32K, Bt1: 32K..64K, Ts: 64K..80K, Ts2: 80K..96K, Wt: 96K.. +18432, ml/wl dbuf: tail
    char* Ts  = lds + 65536;
    char* Ts2 = lds + 81920;
    char* Wt  = lds + 98304;
    const unsigned short* Ab = Amat + (long)b * CC * KTOT;
    bf16x8 af[2][8];
    f32x4 f0v[2], wbv[2];
    #pragma unroll
    for (int fr = 0; fr < 2; ++fr) {
        const unsigned short* arow = Ab + (long)(obase + fr * 16 + lo) * KTOT + hi * 8;
        #pragma unroll
        for (int ks = 0; ks < 8; ++ks) af[fr][ks] = *(const bf16x8*)(arow + ks * 32);
        int o0f = obase + fr * 16 + hi * 4;
        f0v[fr] = *(const f32x4*)(f0a + b * CC + o0f);
        wbv[fr] = *(const f32x4*)(wba + b * CC + o0f);
    }
    int swz = (lo & 7) << 4;
    f32x4 accF[9];
    #pragma unroll
    for (int mt = 0; mt < 9; ++mt) accF[mt] = (f32x4){0.f, 0.f, 0.f, 0.f};
    const char* Bbase = (const char*)Binv + (long)b * NP * 512;
    if (DO_FWD && t < 480) *(unsigned int*)(Wt + 129 * 128 + t * 4) = 0u;   // zero pad rows once

    uint4 pB0 = {}, pB1 = {}, pB2 = {}, pB3 = {};
    float pmv = 0.f, pwv = 0.f;
    auto issue = [&](int chunk) {
        const char* Bsrc = Bbase + (long)chunk * 64 * 512;
        pB0 = *(const uint4*)(Bsrc + 0 * 8192 + t * 16);
        pB1 = *(const uint4*)(Bsrc + 1 * 8192 + t * 16);
        pB2 = *(const uint4*)(Bsrc + 2 * 8192 + t * 16);
        pB3 = *(const uint4*)(Bsrc + 3 * 8192 + t * 16);
        if (t < 64) {
            pmv = maskp[(long)b * NP + chunk * 64 + t];
            pwv = warr[(long)b * NP + chunk * 64 + t];
        }
    };
    auto commit = [&](char* Bq, float* mq) {
        int o = 0 * 8192 + t * 16; *(uint4*)(Bq + (o ^ (((o >> 9) & 7) << 4))) = pB0;
        o = 1 * 8192 + t * 16;     *(uint4*)(Bq + (o ^ (((o >> 9) & 7) << 4))) = pB1;
        o = 2 * 8192 + t * 16;     *(uint4*)(Bq + (o ^ (((o >> 9) & 7) << 4))) = pB2;
        o = 3 * 8192 + t * 16;     *(uint4*)(Bq + (o ^ (((o >> 9) & 7) << 4))) = pB3;
        if (t < 64) { mq[t] = pmv; mq[64 + t] = pwv; }
    };

    {   // prologue: chunk s -> Bt0; issue chunk s+FS
        issue(s);
        commit(lds, (float*)(lds + 116736));
        if (s + FSPLITS < NCH) issue(s + FSPLITS);
    }
    bar_lgkm();

    int iter = 0;
    for (int chunk = s; chunk < NCH; chunk += FSPLITS, ++iter) {
        int P = iter & 1;
        char* BtP = lds + P * 32768;
        char* BtQ = lds + (P ^ 1) * 32768;
        float* mqP = (float*)(lds + 116736 + P * 512);
        float* mqQ = (float*)(lds + 116736 + (P ^ 1) * 512);
        int nbase = chunk * 64;
        int nc = chunk + FSPLITS;
        // ---- phase A: commit next tile / issue next-next / transpose / inverse MFMA / epilogue ----
        if (nc < NCH) {
            commit(BtQ, mqQ);                 // loads issued a full iteration ago
            if (nc + FSPLITS < NCH) issue(nc + FSPLITS);
        }
        if (DO_FWD) {   // Wt = transpose(BtP cols 0..127) + mask row
            int g = t >> 6, n_ = t & 63;
            int rkey = (n_ & 7) << 4;
            int raddr = n_ * 512 + g * 32;
            u16x8 r0 = *(const u16x8*)(BtP + (raddr ^ rkey));
            u16x8 r1 = *(const u16x8*)(BtP + ((raddr + 16) ^ rkey));
            #pragma unroll
            for (int i = 0; i < 8; ++i) {
                int mr = g * 16 + i;
                *(unsigned short*)(Wt + ((mr * 128 + n_ * 2) ^ ((mr & 7) << 4))) = r0[i];
            }
            #pragma unroll
            for (int i = 0; i < 8; ++i) {
                int mr = g * 16 + 8 + i;
                *(unsigned short*)(Wt + ((mr * 128 + n_ * 2) ^ ((mr & 7) << 4))) = r1[i];
            }
            if (t < 64) *(unsigned short*)(Wt + 128 * 128 + t * 2) = f2bf(mqP[t]);
        }
        f32x4 acc[2][2];
        #pragma unroll
        for (int fr = 0; fr < 2; ++fr)
            #pragma unroll
            for (int fn = 0; fn < 2; ++fn) acc[fr][fn] = (f32x4){0.f, 0.f, 0.f, 0.f};
        #pragma unroll
        for (int ks = 0; ks < 8; ++ks) {
            #pragma unroll
            for (int fn = 0; fn < 2; ++fn) {
                int boff = ((nwin + fn * 16 + lo) << 9) + (ks << 6) + (hi << 4);
                bf16x8 bb = *(const bf16x8*)(BtP + (boff ^ swz));
                acc[0][fn] = __builtin_amdgcn_mfma_f32_16x16x32_bf16(af[0][ks], bb, acc[0][fn], 0, 0, 0);
                acc[1][fn] = __builtin_amdgcn_mfma_f32_16x16x32_bf16(af[1][ks], bb, acc[1][fn], 0, 0, 0);
            }
        }
        #pragma unroll
        for (int fr = 0; fr < 2; ++fr) {
            int o0 = obase + fr * 16 + hi * 4;
            #pragma unroll
            for (int fn = 0; fn < 2; ++fn) {
                int n = nwin + fn * 16 + lo;
                float mv = mqP[n];
                u16x4 pk;
                #pragma unroll
                for (int r = 0; r < 4; ++r) {
                    float v = acc[fr][fn][r] + f0v[fr][r] * mv + wbv[fr][r];
                    if (DOGELU) v = gelu_exact(v);
                    pk[r] = f2bf(v);
                    if (DO_FWD)
                        *(unsigned short*)(Ts2 + (((o0 + r) * 128 + n * 2) ^ (((o0 + r) & 7) << 4))) = f2bf(v * mqP[64 + n]);
                }
                *(u16x4*)(Ts + (((n << 8) + (o0 << 1)) ^ ((n & 7) << 4))) = pk;
            }
        }
        bar_lgkm();   // (c) Ts/Ts2/Wt built; BtQ committed
        // ---- phase B: global writeback + forward MFMA ----
        char* Bdst = (char*)Binv + ((long)b * NP + nbase) * 512 + 256;
        #pragma unroll
        for (int pass = 0; pass < 2; ++pass) {
            int n = pass * 32 + (t >> 4), seg = t & 15;
            uint4 v = *(const uint4*)(Ts + (((n << 8) + (seg << 4)) ^ ((n & 7) << 4)));
            *(uint4*)(Bdst + (long)n * 512 + seg * 16) = v;
        }
        if (DO_FWD) {
            int ct = wv * 16;
            #pragma unroll
            for (int ks2 = 0; ks2 < 2; ++ks2) {
                int ar = ct + lo;
                bf16x8 a = *(const bf16x8*)(Ts2 + ((ar * 128 + ks2 * 64 + hi * 16) ^ ((ar & 7) << 4)));
                #pragma unroll
                for (int mt = 0; mt < 9; ++mt) {
                    int mrow = mt * 16 + lo;
                    bf16x8 bb = *(const bf16x8*)(Wt + ((mrow * 128 + ks2 * 64 + hi * 16) ^ ((mrow & 7) << 4)));
                    accF[mt] = __builtin_amdgcn_mfma_f32_16x16x32_bf16(a, bb, accF[mt], 0, 0, 0);
                }
            }
        }
        bar_lgkm();   // (end) Ts/Ts2/Wt reads done before next iter rewrites
    }
    if (DO_FWD) {
        unsigned short* pb = pxcs + ((long)s * BATCH + b) * CC * MODES;
        #pragma unroll
        for (int mt = 0; mt < 9; ++mt)
            #pragma unroll
            for (int r = 0; r < 4; ++r)
                pb[(long)(wv * 16 + hi * 4 + r) * MODES + mt * 16 + lo] = f2bf(accF[mt][r]);
    }
}

// ---------- head: out = gelu(hT@fc1 + b1) @ fc2 + b2 ----------
__global__ __launch_bounds__(256) void head_mfma(const unsigned short* __restrict__ Binv,
        const unsigned short* __restrict__ fc1t, const float* __restrict__ b1,
        const float* __restrict__ fc2, const float* __restrict__ b2, float* __restrict__ out) {
    int t = threadIdx.x, wv = t >> 6, l = t & 63, lo = l & 15, hi = l >> 4;
    int b = blockIdx.y;
    int nb = (blockIdx.x * 4 + wv) * 16;
    const unsigned short* Arow = Binv + ((long)b * NP + nb + lo) * KTOT + 128 + hi * 8;
    f32x4 acc[8];
    #pragma unroll
    for (int ft = 0; ft < 8; ++ft) acc[ft] = (f32x4){0.f, 0.f, 0.f, 0.f};
    #pragma unroll
    for (int ks = 0; ks < 4; ++ks) {
        bf16x8 a = *(const bf16x8*)(Arow + ks * 32);
        #pragma unroll
        for (int ft = 0; ft < 8; ++ft) {
            bf16x8 bv = *(const bf16x8*)(fc1t + (ft * 16 + lo) * 128 + ks * 32 + hi * 8);
            acc[ft] = __builtin_amdgcn_mfma_f32_16x16x32_bf16(a, bv, acc[ft], 0, 0, 0);
        }
    }
    float s[4] = {0.f, 0.f, 0.f, 0.f};
    #pragma unroll
    for (int ft = 0; ft < 8; ++ft) {
        int f = ft * 16 + lo;
        float b1f = b1[f], f2f = fc2[f];
        #pragma unroll
        for (int r = 0; r < 4; ++r) s[r] += gelu_exact(acc[ft][r] + b1f) * f2f;
    }
    float b2v = b2[0];
    #pragma unroll
    for (int r = 0; r < 4; ++r) {
        float v = s[r];
        v += __shfl_xor(v, 1); v += __shfl_xor(v, 2);
        v += __shfl_xor(v, 4); v += __shfl_xor(v, 8);
        if (lo == 0) out[(long)b * NN + nb + hi * 4 + r] = v + b2v;
    }
}

extern "C" void kernel_launch(void* const* d_in, const int* in_sizes, int n_in,
                              void* d_out, int out_size, void* d_ws, size_t ws_size,
                              hipStream_t stream) {
    const float* x     = (const float*)d_in[0];
    const float* mask  = (const float*)d_in[1];
    const float* nodes = (const float*)d_in[2];
    const float* wts   = (const float*)d_in[3];
    // d_in[4] directed_edges, d_in[5] edge_gradient_weights: dead (x3 never added)
    const float* modes = (const float*)d_in[6];
    const float* fc0w  = (const float*)d_in[7];
    const float* fc0b  = (const float*)d_in[8];
    const float* spwc  = (const float*)d_in[9];
    const float* spws  = (const float*)d_in[10];
    const float* spw0  = (const float*)d_in[11];
    const float* ww    = (const float*)d_in[12];
    const float* wb    = (const float*)d_in[13];
    // d_in[14] gw_w, d_in[15] gw_b: dead
    const float* fc1w  = (const float*)d_in[16];
    const float* fc1b  = (const float*)d_in[17];
    const float* fc2w  = (const float*)d_in[18];
    const float* fc2b  = (const float*)d_in[19];

    char* p = (char*)d_ws;
    auto alloc = [&](size_t bytes) { char* r = p; p += (bytes + 255) & ~255UL; return r; };
    unsigned short* Binv = (unsigned short*)alloc((size_t)BATCH * NP * KTOT * 2);
    unsigned short* Amat = (unsigned short*)alloc((size_t)BATCH * CC * KTOT * 2);
    unsigned short* fc1t = (unsigned short*)alloc((size_t)CC * 128 * 2);
    unsigned short* pxcs = (unsigned short*)alloc((size_t)FSPLITS * BATCH * CC * MODES * 2);
    float* xcb  = (float*)alloc((size_t)BATCH * CC * KK * 4);
    float* xsb  = (float*)alloc((size_t)BATCH * CC * KK * 4);
    float* x0b  = (float*)alloc((size_t)BATCH * CC * 4);
    float* f0a  = (float*)alloc((size_t)BATCH * CC * 4);
    float* wba  = (float*)alloc((size_t)BATCH * CC * 4);
    float* maskp = (float*)alloc((size_t)BATCH * NP * 4);
    float* warr  = (float*)alloc((size_t)BATCH * NP * 4);

    fc1t_kernel<<<64, 256, 0, stream>>>(fc1w, fc1t);
    lift_fused<<<dim3(FSPLITS, BATCH), 512, 0, stream>>>(x, fc0w, fc0b, nodes, mask, wts,
                                                         modes, Binv, maskp, warr, pxcs);

    for (int l = 0; l < NLAYER; ++l) {
        reduce_kernel<<<(8 * BATCH * CC * MODES) / 256, 256, 0, stream>>>(pxcs, xcb, xsb, x0b);
        mix_kernel<<<dim3(CC, BATCH), 1024, 0, stream>>>(xcb, xsb, x0b, spwc, spws, spw0,
                                                         ww, wb, Amat, f0a, wba, l);
        if (l < NLAYER - 1)
            fused_inv<1, 1><<<dim3(FSPLITS, BATCH), 512, 0, stream>>>(
                Amat, Binv, f0a, wba, maskp, warr, pxcs);
        else
            fused_inv<0, 0><<<dim3(FSPLITS, BATCH), 512, 0, stream>>>(
                Amat, Binv, f0a, wba, maskp, warr, pxcs);
    }
    head_mfma<<<dim3(NN / 64, BATCH), 256, 0, stream>>>(Binv, fc1t, fc1b, fc2w, fc2b, (float*)d_out);
}

// Round 14
// 191.767 us; speedup vs baseline: 1.0937x; 1.0937x over previous
//
#include <hip/hip_runtime.h>
#include <math.h>

#define NN 40000
#define NP 40064          // 313 * 128, padded node count
#define CC 128
#define KK 64
#define BATCH 2
#define NLAYER 4
#define FSPLITS 128
#define MODES 144         // 64 cos + 64 sin + 1 mask-mode + 15 zero pad
#define KTOT 256          // inverse GEMM contraction: 64 bc + 64 bs + 128 h
#define NCH 626           // NP / 64
#define NVCH 625          // chunks with valid nodes (625*64 == NN exactly)

typedef __attribute__((ext_vector_type(8))) short bf16x8;
typedef __attribute__((ext_vector_type(4))) float f32x4;
typedef __attribute__((ext_vector_type(4))) unsigned short u16x4;
typedef __attribute__((ext_vector_type(8))) unsigned short u16x8;

__device__ __forceinline__ float gelu_exact(float x) {
    return 0.5f * x * (1.0f + erff(x * 0.70710678118654752f));
}
__device__ __forceinline__ unsigned short f2bf(float x) {   // RNE float->bf16
    unsigned int u = __float_as_uint(x);
    u += 0x7FFFu + ((u >> 16) & 1u);
    return (unsigned short)(u >> 16);
}
__device__ __forceinline__ float bf2f(unsigned short v) {
    return __uint_as_float(((unsigned int)v) << 16);
}

// ---------- lift + basis + layer-0 forward partials (fully fused; also emits fc1t) ----------
// grid (FSPLITS, BATCH), 512 thr. Computes sincos basis in-kernel, writes Binv bc/bs + h,
// maskp/warr, layer-0 forward partials; blocks (s<32, b==0) also transpose fc1 -> fc1t.
__global__ __launch_bounds__(512) void lift_fused(const float* __restrict__ x,
        const float* __restrict__ w, const float* __restrict__ bvec,
        const float* __restrict__ nodes, const float* __restrict__ mask,
        const float* __restrict__ wts, const float* __restrict__ modes,
        const float* __restrict__ fc1w, unsigned short* __restrict__ fc1t,
        unsigned short* __restrict__ Binv, float* __restrict__ maskp,
        float* __restrict__ warr, unsigned short* __restrict__ pxcs) {
    int s = blockIdx.x, b = blockIdx.y;
    int t = threadIdx.x, wv = t >> 6, l = t & 63, lo = l & 15, hi = l >> 4;
    if (b == 0 && s < 32) {   // fc1 transpose, 1 elem/thread (each written exactly once)
        int idx = s * 512 + t;
        int f = idx >> 7, c = idx & 127;
        fc1t[f * 128 + c] = f2bf(fc1w[c * 128 + f]);
    }
    __shared__ __align__(16) char lds[53504];
    char* Ts   = lds;              // [64 n][128 c]u16 (16 KB), h, swizzled
    char* Ts2  = lds + 16384;      // [128 c][64 n]u16 (16 KB), h*w, swizzled
    char* Wt   = lds + 32768;      // [144 mode][64 n]u16 rows 128B (18432 B)
    float* xl  = (float*)(lds + 51200);   // x chunk [64][3]  (768 B)
    float* ndl = (float*)(lds + 51968);   // nodes [64][2]    (512 B)
    float* wl  = (float*)(lds + 52480);   // w per n          (256 B)
    float* ml  = (float*)(lds + 52736);   // m per n          (256 B)
    float* sm  = (float*)(lds + 52992);   // modes [64][2]    (512 B)
    int c = t & 127, ng = t >> 7;
    float w0 = w[c], w1 = w[CC + c], w2 = w[2 * CC + c], bv = bvec[c];
    f32x4 accF[9];
    #pragma unroll
    for (int mt = 0; mt < 9; ++mt) accF[mt] = (f32x4){0.f, 0.f, 0.f, 0.f};
    if (t < 128) sm[t] = modes[t];
    if (t < 480) *(unsigned int*)(Wt + 129 * 128 + t * 4) = 0u;   // zero pad rows once

    // per-chunk small fetch: one float per thread (x | nodes | wts | mask)
    auto fetch = [&](int chunk) -> float {
        if (chunk >= NVCH) return 0.f;   // pad chunk
        long base = (long)b * NN + chunk * 64;
        if (t < 192) return x[base * 3 + t];
        if (t < 320) return nodes[base * 2 + (t - 192)];
        if (t < 384) return wts[base + (t - 320)];
        if (t < 448) return mask[base + (t - 384)];
        return 0.f;
    };
    float pf = fetch(s);

    for (int chunk = s; chunk < NCH; chunk += FSPLITS) {
        int nbase = chunk * 64;
        __syncthreads();   // (a) prev iter's Ts/Ts2/Wt reads complete
        {   // commit prefetched float
            if (t < 192)      xl[t] = pf;
            else if (t < 320) ndl[t - 192] = pf;
            else if (t < 384) wl[t - 320] = pf;
            else if (t < 448) ml[t - 384] = pf;
        }
        int nc = chunk + FSPLITS;
        if (nc < NCH) pf = fetch(nc);
        __syncthreads();   // (b)
        {   // sincos role: thread = (n_, 8 modes); write Wt + Binv bc/bs
            int n_ = t & 63, g = t >> 6;
            float nx = ndl[n_ * 2], ny = ndl[n_ * 2 + 1];
            float m = ml[n_];
            u16x8 cosr, sinr;
            #pragma unroll
            for (int j = 0; j < 8; ++j) {
                int k = g * 8 + j;
                float tv = nx * sm[2 * k] + ny * sm[2 * k + 1];
                float sv, cv;
                __sincosf(tv, &sv, &cv);
                unsigned short cb = f2bf(cv * m), sb = f2bf(sv * m);
                cosr[j] = cb; sinr[j] = sb;
                *(unsigned short*)(Wt + ((k * 128 + n_ * 2) ^ ((k & 7) << 4))) = cb;
                *(unsigned short*)(Wt + (((64 + k) * 128 + n_ * 2) ^ (((64 + k) & 7) << 4))) = sb;
            }
            char* brow = (char*)Binv + ((long)b * NP + nbase + n_) * 512 + g * 16;
            *(u16x8*)brow = cosr;
            *(u16x8*)(brow + 128) = sinr;
            if (t < 64) {
                *(unsigned short*)(Wt + 128 * 128 + n_ * 2) = f2bf(m);
                maskp[(long)b * NP + nbase + n_] = m;
                warr[(long)b * NP + nbase + n_] = wl[n_];
            }
        }
        {   // h role: compute h, write Ts (h) and Ts2 (h*w)
            u16x8 hv0, hv1;
            #pragma unroll
            for (int j = 0; j < 16; ++j) {
                int n = ng * 16 + j;
                float h = bv + xl[n * 3] * w0 + xl[n * 3 + 1] * w1 + xl[n * 3 + 2] * w2;
                unsigned short hb = f2bf(h);
                unsigned short hwb = f2bf(h * wl[n]);
                if (j < 8) hv0[j] = hwb; else hv1[j - 8] = hwb;
                *(unsigned short*)(Ts + (((n << 8) + c * 2) ^ ((n & 7) << 4))) = hb;
            }
            int base2 = c * 128 + ng * 32;
            *(u16x8*)(Ts2 + (base2 ^ ((c & 7) << 4))) = hv0;
            *(u16x8*)(Ts2 + ((base2 + 16) ^ ((c & 7) << 4))) = hv1;
        }
        __syncthreads();   // (c)
        char* Bdst = (char*)Binv + ((long)b * NP + nbase) * 512 + 256;
        #pragma unroll
        for (int pass = 0; pass < 2; ++pass) {
            int n = pass * 32 + (t >> 4), seg = t & 15;
            uint4 v = *(const uint4*)(Ts + (((n << 8) + (seg << 4)) ^ ((n & 7) << 4)));
            *(uint4*)(Bdst + (long)n * 512 + seg * 16) = v;
        }
        int ct = wv * 16;
        #pragma unroll
        for (int ks2 = 0; ks2 < 2; ++ks2) {
            int ar = ct + lo;
            bf16x8 a = *(const bf16x8*)(Ts2 + ((ar * 128 + ks2 * 64 + hi * 16) ^ ((ar & 7) << 4)));
            #pragma unroll
            for (int mt = 0; mt < 9; ++mt) {
                int mrow = mt * 16 + lo;
                bf16x8 bb = *(const bf16x8*)(Wt + ((mrow * 128 + ks2 * 64 + hi * 16) ^ ((mrow & 7) << 4)));
                accF[mt] = __builtin_amdgcn_mfma_f32_16x16x32_bf16(a, bb, accF[mt], 0, 0, 0);
            }
        }
    }
    unsigned short* pb = pxcs + ((long)s * BATCH + b) * CC * MODES;
    #pragma unroll
    for (int mt = 0; mt < 9; ++mt)
        #pragma unroll
        for (int r = 0; r < 4; ++r)
            pb[(long)(wv * 16 + hi * 4 + r) * MODES + mt * 16 + lo] = f2bf(accF[mt][r]);
}

// ---------- reduce split partials (bf16) -> xc, xs, x0 ----------
__global__ __launch_bounds__(256) void reduce_kernel(const unsigned short* __restrict__ pxcs,
        float* __restrict__ xc, float* __restrict__ xs, float* __restrict__ x0) {
    int gid = blockIdx.x * 256 + threadIdx.x;    // 8 * 36864 = 294912 total
    int idx = gid >> 3, sg = gid & 7;
    float a = 0.f;
    #pragma unroll
    for (int j = 0; j < 16; ++j)
        a += bf2f(pxcs[(long)(sg * 16 + j) * (BATCH * CC * MODES) + idx]);
    a += __shfl_xor(a, 1); a += __shfl_xor(a, 2); a += __shfl_xor(a, 4);
    if (sg == 0) {
        int m = idx % MODES, bc_ = idx / MODES;
        if (m < 64)        xc[bc_ * KK + m] = a;
        else if (m < 128)  xs[bc_ * KK + m - 64] = a;
        else if (m == 128) x0[bc_] = a;
    }
}

// ---------- mix: assemble A=[2fc|-2fs|ww] bf16, f0/wb fp32 (16 i-groups for TLP) ----------
__global__ __launch_bounds__(1024) void mix_kernel(const float* __restrict__ xc,
        const float* __restrict__ xs, const float* __restrict__ x0,
        const float* __restrict__ wc, const float* __restrict__ wsp,
        const float* __restrict__ w0, const float* __restrict__ ww,
        const float* __restrict__ wbias, unsigned short* __restrict__ A,
        float* __restrict__ f0a, float* __restrict__ wba, int layer) {
    int o = blockIdx.x, b = blockIdx.y;
    int k = threadIdx.x & 63, ig = threadIdx.x >> 6;   // ig 0..15
    const float* wcl = wc  + (long)layer * CC * CC * KK;
    const float* wsl = wsp + (long)layer * CC * CC * KK;
    float fc = 0.f, fs = 0.f;
    #pragma unroll
    for (int j = 0; j < 8; ++j) {
        int i = ig * 8 + j;
        float xci = xc[(b * CC + i) * KK + k];
        float xsi = xs[(b * CC + i) * KK + k];
        float wcv = wcl[((long)i * CC + o) * KK + k];
        float wsv = wsl[((long)i * CC + o) * KK + k];
        fc += xci * wcv + xsi * wsv;
        fs += xci * wsv - xsi * wcv;
    }
    __shared__ float rc[16][64], rs[16][64];
    rc[ig][k] = fc; rs[ig][k] = fs;
    __syncthreads();
    unsigned short* Ar = A + ((long)b * CC + o) * KTOT;
    if (ig == 0) {
        fc = 0.f; fs = 0.f;
        #pragma unroll
        for (int j = 0; j < 16; ++j) { fc += rc[j][k]; fs += rs[j][k]; }
        Ar[k]      = f2bf(2.f * fc);
        Ar[64 + k] = f2bf(-2.f * fs);
    } else if (ig == 1) {
        const float* wwl = ww + ((long)layer * CC + o) * CC;
        Ar[128 + k] = f2bf(wwl[k]);
        Ar[192 + k] = f2bf(wwl[64 + k]);
    } else if (ig == 2) {
        const float* w0l = w0 + (long)layer * CC * CC;
        float p = x0[b * CC + k] * w0l[(long)k * CC + o]
                + x0[b * CC + 64 + k] * w0l[(long)(64 + k) * CC + o];
        #pragma unroll
        for (int off = 32; off > 0; off >>= 1) p += __shfl_down(p, off, 64);
        if (k == 0) { f0a[b * CC + o] = p; wba[b * CC + o] = wbias[layer * CC + o]; }
    }
}

// ---------- fused inverse + next-layer forward partials ----------
// grid (FSPLITS, BATCH), 512 thr = 8 waves; wave tile 16o x 64n; grid-stride over n-chunks.
template <int DO_FWD, int DOGELU>
__global__ __launch_bounds__(512) void fused_inv(const unsigned short* __restrict__ Amat,
        unsigned short* Binv, const float* __restrict__ f0a, const float* __restrict__ wba,
        const float* __restrict__ maskp, const float* __restrict__ warr,
        unsigned short* __restrict__ pxcs) {
    int s = blockIdx.x, b = blockIdx.y;
    int t = threadIdx.x, wv = t >> 6, l = t & 63, lo = l & 15, hi = l >> 4;
    __shared__ __align__(16) char lds[51712];
    char* Btile = lds;            // 32 KB staging [64 n][512B]; overlaid after use by:
    char* Ts    = lds;            //   [64 n][128 o]u16 (16 KB)
    char* Ts2   = lds + 16384;    //   [128 c][64 n]u16 (16 KB), holds h*w
    char* Wt    = lds + 32768;    // [144 mode][64 n]u16 rows 128B (18432 B)
    float* ml   = (float*)(lds + 51200);  // mask per n
    float* wl   = (float*)(lds + 51456);  // w per n
    const unsigned short* Ab = Amat + (long)b * CC * KTOT;
    bf16x8 af[8];
    {
        const unsigned short* arow = Ab + (long)(wv * 16 + lo) * KTOT + hi * 8;
        #pragma unroll
        for (int ks = 0; ks < 8; ++ks) af[ks] = *(const bf16x8*)(arow + ks * 32);
    }
    int o0 = wv * 16 + hi * 4;
    f32x4 f0v = *(const f32x4*)(f0a + b * CC + o0);
    f32x4 wbv = *(const f32x4*)(wba + b * CC + o0);
    int swz = (lo & 7) << 4;
    f32x4 accF[9];
    #pragma unroll
    for (int mt = 0; mt < 9; ++mt) accF[mt] = (f32x4){0.f, 0.f, 0.f, 0.f};
    const char* Bbase = (const char*)Binv + (long)b * NP * 512;
    if (DO_FWD && t < 480) *(unsigned int*)(Wt + 129 * 128 + t * 4) = 0u;   // zero pad rows once

    uint4 pB0 = {}, pB1 = {}, pB2 = {}, pB3 = {};
    float pmv = 0.f, pwv = 0.f;
    {   // prefetch first chunk
        const char* Bsrc = Bbase + (long)s * 64 * 512;
        pB0 = *(const uint4*)(Bsrc + 0 * 8192 + t * 16);
        pB1 = *(const uint4*)(Bsrc + 1 * 8192 + t * 16);
        pB2 = *(const uint4*)(Bsrc + 2 * 8192 + t * 16);
        pB3 = *(const uint4*)(Bsrc + 3 * 8192 + t * 16);
        if (t < 64) { pmv = maskp[(long)b * NP + s * 64 + t]; pwv = warr[(long)b * NP + s * 64 + t]; }
    }

    for (int chunk = s; chunk < NCH; chunk += FSPLITS) {
        int nbase = chunk * 64;
        __syncthreads();   // previous iter's Ts/Ts2/Wt reads complete
        {   // commit prefetched regs to LDS (swizzled)
            int o = 0 * 8192 + t * 16; *(uint4*)(Btile + (o ^ (((o >> 9) & 7) << 4))) = pB0;
            o = 1 * 8192 + t * 16;     *(uint4*)(Btile + (o ^ (((o >> 9) & 7) << 4))) = pB1;
            o = 2 * 8192 + t * 16;     *(uint4*)(Btile + (o ^ (((o >> 9) & 7) << 4))) = pB2;
            o = 3 * 8192 + t * 16;     *(uint4*)(Btile + (o ^ (((o >> 9) & 7) << 4))) = pB3;
            if (t < 64) { ml[t] = pmv; wl[t] = pwv; }
        }
        int nc = chunk + FSPLITS;
        if (nc < NCH) {   // issue next chunk's loads
            const char* Bsrc = Bbase + (long)nc * 64 * 512;
            pB0 = *(const uint4*)(Bsrc + 0 * 8192 + t * 16);
            pB1 = *(const uint4*)(Bsrc + 1 * 8192 + t * 16);
            pB2 = *(const uint4*)(Bsrc + 2 * 8192 + t * 16);
            pB3 = *(const uint4*)(Bsrc + 3 * 8192 + t * 16);
            if (t < 64) { pmv = maskp[(long)b * NP + nc * 64 + t]; pwv = warr[(long)b * NP + nc * 64 + t]; }
        }
        __syncthreads();
        if (DO_FWD) {   // build Wt = transpose(Btile cols 0..127) + mask row (reads-only Btile)
            int g = t >> 6, n_ = t & 63;
            int rkey = (n_ & 7) << 4;
            int raddr = n_ * 512 + g * 32;
            u16x8 r0 = *(const u16x8*)(Btile + (raddr ^ rkey));
            u16x8 r1 = *(const u16x8*)(Btile + ((raddr + 16) ^ rkey));
            #pragma unroll
            for (int i = 0; i < 8; ++i) {
                int mr = g * 16 + i;
                *(unsigned short*)(Wt + ((mr * 128 + n_ * 2) ^ ((mr & 7) << 4))) = r0[i];
            }
            #pragma unroll
            for (int i = 0; i < 8; ++i) {
                int mr = g * 16 + 8 + i;
                *(unsigned short*)(Wt + ((mr * 128 + n_ * 2) ^ ((mr & 7) << 4))) = r1[i];
            }
            if (t < 64) *(unsigned short*)(Wt + 128 * 128 + t * 2) = f2bf(ml[t]);
        }
        f32x4 acc[4];
        #pragma unroll
        for (int fn = 0; fn < 4; ++fn) acc[fn] = (f32x4){0.f, 0.f, 0.f, 0.f};
        #pragma unroll
        for (int ks = 0; ks < 8; ++ks) {
            #pragma unroll
            for (int fn = 0; fn < 4; ++fn) {
                int boff = ((fn * 16 + lo) << 9) + (ks << 6) + (hi << 4);
                bf16x8 bb = *(const bf16x8*)(Btile + (boff ^ swz));
                acc[fn] = __builtin_amdgcn_mfma_f32_16x16x32_bf16(af[ks], bb, acc[fn], 0, 0, 0);
            }
        }
        __syncthreads();   // Btile reads (MFMA + transpose) done; overlay with Ts/Ts2
        #pragma unroll
        for (int fn = 0; fn < 4; ++fn) {
            int n = fn * 16 + lo;
            float mv = ml[n];
            u16x4 pk;
            #pragma unroll
            for (int r = 0; r < 4; ++r) {
                float v = acc[fn][r] + f0v[r] * mv + wbv[r];
                if (DOGELU) v = gelu_exact(v);
                pk[r] = f2bf(v);
                if (DO_FWD)
                    *(unsigned short*)(Ts2 + (((o0 + r) * 128 + n * 2) ^ (((o0 + r) & 7) << 4))) = f2bf(v * wl[n]);
            }
            *(u16x4*)(Ts + (((n << 8) + (o0 << 1)) ^ ((n & 7) << 4))) = pk;
        }
        __syncthreads();
        char* Bdst = (char*)Binv + ((long)b * NP + nbase) * 512 + 256;
        #pragma unroll
        for (int pass = 0; pass < 2; ++pass) {
            int n = pass * 32 + (t >> 4), seg = t & 15;
            uint4 v = *(const uint4*)(Ts + (((n << 8) + (seg << 4)) ^ ((n & 7) << 4)));
            *(uint4*)(Bdst + (long)n * 512 + seg * 16) = v;
        }
        if (DO_FWD) {
            int ct = wv * 16;
            #pragma unroll
            for (int ks2 = 0; ks2 < 2; ++ks2) {
                int ar = ct + lo;
                bf16x8 a = *(const bf16x8*)(Ts2 + ((ar * 128 + ks2 * 64 + hi * 16) ^ ((ar & 7) << 4)));
                #pragma unroll
                for (int mt = 0; mt < 9; ++mt) {
                    int mrow = mt * 16 + lo;
                    bf16x8 bb = *(const bf16x8*)(Wt + ((mrow * 128 + ks2 * 64 + hi * 16) ^ ((mrow & 7) << 4)));
                    accF[mt] = __builtin_amdgcn_mfma_f32_16x16x32_bf16(a, bb, accF[mt], 0, 0, 0);
                }
            }
        }
    }
    if (DO_FWD) {
        unsigned short* pb = pxcs + ((long)s * BATCH + b) * CC * MODES;
        #pragma unroll
        for (int mt = 0; mt < 9; ++mt)
            #pragma unroll
            for (int r = 0; r < 4; ++r)
                pb[(long)(wv * 16 + hi * 4 + r) * MODES + mt * 16 + lo] = f2bf(accF[mt][r]);
    }
}

// ---------- head: out = gelu(hT@fc1 + b1) @ fc2 + b2 ----------
__global__ __launch_bounds__(256) void head_mfma(const unsigned short* __restrict__ Binv,
        const unsigned short* __restrict__ fc1t, const float* __restrict__ b1,
        const float* __restrict__ fc2, const float* __restrict__ b2, float* __restrict__ out) {
    int t = threadIdx.x, wv = t >> 6, l = t & 63, lo = l & 15, hi = l >> 4;
    int b = blockIdx.y;
    int nb = (blockIdx.x * 4 + wv) * 16;
    const unsigned short* Arow = Binv + ((long)b * NP + nb + lo) * KTOT + 128 + hi * 8;
    f32x4 acc[8];
    #pragma unroll
    for (int ft = 0; ft < 8; ++ft) acc[ft] = (f32x4){0.f, 0.f, 0.f, 0.f};
    #pragma unroll
    for (int ks = 0; ks < 4; ++ks) {
        bf16x8 a = *(const bf16x8*)(Arow + ks * 32);
        #pragma unroll
        for (int ft = 0; ft < 8; ++ft) {
            bf16x8 bv = *(const bf16x8*)(fc1t + (ft * 16 + lo) * 128 + ks * 32 + hi * 8);
            acc[ft] = __builtin_amdgcn_mfma_f32_16x16x32_bf16(a, bv, acc[ft], 0, 0, 0);
        }
    }
    float s[4] = {0.f, 0.f, 0.f, 0.f};
    #pragma unroll
    for (int ft = 0; ft < 8; ++ft) {
        int f = ft * 16 + lo;
        float b1f = b1[f], f2f = fc2[f];
        #pragma unroll
        for (int r = 0; r < 4; ++r) s[r] += gelu_exact(acc[ft][r] + b1f) * f2f;
    }
    float b2v = b2[0];
    #pragma unroll
    for (int r = 0; r < 4; ++r) {
        float v = s[r];
        v += __shfl_xor(v, 1); v += __shfl_xor(v, 2);
        v += __shfl_xor(v, 4); v += __shfl_xor(v, 8);
        if (lo == 0) out[(long)b * NN + nb + hi * 4 + r] = v + b2v;
    }
}

extern "C" void kernel_launch(void* const* d_in, const int* in_sizes, int n_in,
                              void* d_out, int out_size, void* d_ws, size_t ws_size,
                              hipStream_t stream) {
    const float* x     = (const float*)d_in[0];
    const float* mask  = (const float*)d_in[1];
    const float* nodes = (const float*)d_in[2];
    const float* wts   = (const float*)d_in[3];
    // d_in[4] directed_edges, d_in[5] edge_gradient_weights: dead (x3 never added)
    const float* modes = (const float*)d_in[6];
    const float* fc0w  = (const float*)d_in[7];
    const float* fc0b  = (const float*)d_in[8];
    const float* spwc  = (const float*)d_in[9];
    const float* spws  = (const float*)d_in[10];
    const float* spw0  = (const float*)d_in[11];
    const float* ww    = (const float*)d_in[12];
    const float* wb    = (const float*)d_in[13];
    // d_in[14] gw_w, d_in[15] gw_b: dead
    const float* fc1w  = (const float*)d_in[16];
    const float* fc1b  = (const float*)d_in[17];
    const float* fc2w  = (const float*)d_in[18];
    const float* fc2b  = (const float*)d_in[19];

    char* p = (char*)d_ws;
    auto alloc = [&](size_t bytes) { char* r = p; p += (bytes + 255) & ~255UL; return r; };
    unsigned short* Binv = (unsigned short*)alloc((size_t)BATCH * NP * KTOT * 2);
    unsigned short* Amat = (unsigned short*)alloc((size_t)BATCH * CC * KTOT * 2);
    unsigned short* fc1t = (unsigned short*)alloc((size_t)CC * 128 * 2);
    unsigned short* pxcs = (unsigned short*)alloc((size_t)FSPLITS * BATCH * CC * MODES * 2);
    float* xcb  = (float*)alloc((size_t)BATCH * CC * KK * 4);
    float* xsb  = (float*)alloc((size_t)BATCH * CC * KK * 4);
    float* x0b  = (float*)alloc((size_t)BATCH * CC * 4);
    float* f0a  = (float*)alloc((size_t)BATCH * CC * 4);
    float* wba  = (float*)alloc((size_t)BATCH * CC * 4);
    float* maskp = (float*)alloc((size_t)BATCH * NP * 4);
    float* warr  = (float*)alloc((size_t)BATCH * NP * 4);

    lift_fused<<<dim3(FSPLITS, BATCH), 512, 0, stream>>>(x, fc0w, fc0b, nodes, mask, wts,
                                                         modes, fc1w, fc1t, Binv, maskp, warr, pxcs);

    for (int l = 0; l < NLAYER; ++l) {
        reduce_kernel<<<(8 * BATCH * CC * MODES) / 256, 256, 0, stream>>>(pxcs, xcb, xsb, x0b);
        mix_kernel<<<dim3(CC, BATCH), 1024, 0, stream>>>(xcb, xsb, x0b, spwc, spws, spw0,
                                                         ww, wb, Amat, f0a, wba, l);
        if (l < NLAYER - 1)
            fused_inv<1, 1><<<dim3(FSPLITS, BATCH), 512, 0, stream>>>(
                Amat, Binv, f0a, wba, maskp, warr, pxcs);
        else
            fused_inv<0, 0><<<dim3(FSPLITS, BATCH), 512, 0, stream>>>(
                Amat, Binv, f0a, wba, maskp, warr, pxcs);
    }
    head_mfma<<<dim3(NN / 64, BATCH), 256, 0, stream>>>(Binv, fc1t, fc1b, fc2w, fc2b, (float*)d_out);
}